// Round 1
// baseline (288.050 us; speedup 1.0000x reference)
//
#include <hip/hip_runtime.h>
#include <math.h>

#define D_DIM 768
#define T_SEL 8

typedef float f32x4v __attribute__((ext_vector_type(4)));
typedef __bf16 bf16x8 __attribute__((ext_vector_type(8)));

__device__ __forceinline__ float wave_sum(float x) {
#pragma unroll
  for (int o = 32; o > 0; o >>= 1) x += __shfl_xor(x, o, 64);
  return x;
}

__device__ __forceinline__ float wave_min(float x) {
#pragma unroll
  for (int o = 32; o > 0; o >>= 1) x = fminf(x, __shfl_xor(x, o, 64));
  return x;
}

__device__ __forceinline__ unsigned short f2bf(float x) {
  unsigned int u = __float_as_uint(x);
  unsigned int r = (u + 0x7fffu + ((u >> 16) & 1u)) >> 16;
  return (unsigned short)r;
}

__device__ __forceinline__ void async_copy16(void* lds, const void* g) {
  __builtin_amdgcn_global_load_lds(
      (const __attribute__((address_space(1))) unsigned int*)g,
      (__attribute__((address_space(3))) unsigned int*)lds, 16, 0, 0);
}

// ---------------- kernel 1: per-row stats + bf16 convert + top-8 + Jt ----------------
// acc: [0]=ju_sum, [1]=jt_sum, [2]=ortho_sum, [3]=msum
__global__ __launch_bounds__(256) void k_rows(
    const float* __restrict__ v, const float* __restrict__ vhat,
    const float* __restrict__ g, const float* __restrict__ F,
    const int* __restrict__ mask, float* __restrict__ nv2,
    float* __restrict__ true_d, unsigned short* __restrict__ vhat_bf,
    float* __restrict__ acc) {
  const int w = threadIdx.x >> 6;
  const int l = threadIdx.x & 63;
  const int row = blockIdx.x * 4 + w;

  const float4* vr = (const float4*)(vhat + (size_t)row * D_DIM);
  const float4* vv = (const float4*)(v + (size_t)row * D_DIM);
  ushort4* outb = (ushort4*)(vhat_bf + (size_t)row * D_DIM);

  float4 vh[3];
  float s2 = 0.f, td2 = 0.f;
#pragma unroll
  for (int i = 0; i < 3; ++i) {
    vh[i] = vr[i * 64 + l];
    float4 vo = vv[i * 64 + l];
    s2 += vh[i].x * vh[i].x + vh[i].y * vh[i].y + vh[i].z * vh[i].z + vh[i].w * vh[i].w;
    float dx = vh[i].x - vo.x, dy = vh[i].y - vo.y, dz = vh[i].z - vo.z, dw = vh[i].w - vo.w;
    td2 += dx * dx + dy * dy + dz * dz + dw * dw;
    ushort4 us;
    us.x = f2bf(vh[i].x); us.y = f2bf(vh[i].y); us.z = f2bf(vh[i].z); us.w = f2bf(vh[i].w);
    outb[i * 64 + l] = us;
  }
  s2 = wave_sum(s2);
  td2 = wave_sum(td2);
  const float td = sqrtf(fmaxf(td2, 0.f) + 1e-8f);
  if (l == 0) {
    nv2[row] = s2;
    true_d[row] = td;
  }

  // ---- top-8 smallest of the 64 g values (one per lane) ----
  float gcur = g[(size_t)row * 64 + l];
  float selg[T_SEL];
  int selk[T_SEL];
#pragma unroll
  for (int t = 0; t < T_SEL; ++t) {
    float m = wave_min(gcur);
    unsigned long long b = __ballot(gcur == m);
    int src = __ffsll(b) - 1;
    selk[t] = src;
    selg[t] = m;
    if (l == src) gcur = __int_as_float(0x7f800000);  // +inf: remove
  }
  float gsum = 1e-10f;
#pragma unroll
  for (int t = 0; t < T_SEL; ++t) gsum += selg[t];

  const float maskf = (float)mask[row];
  float jt_local = 0.f;
#pragma unroll
  for (int t = 0; t < T_SEL; ++t) {
    const float4* Fr = (const float4*)(F + (size_t)selk[t] * D_DIM);
    float p = 0.f;
#pragma unroll
    for (int i = 0; i < 3; ++i) {
      float4 fv = Fr[i * 64 + l];
      float dx = vh[i].x - fv.x, dy = vh[i].y - fv.y, dz = vh[i].z - fv.z, dw = vh[i].w - fv.w;
      p += dx * dx + dy * dy + dz * dz + dw * dw;
    }
    p = wave_sum(p);
    float dneg = sqrtf(fmaxf(p, 0.f) + 1e-8f);
    float gt = selg[t] / gsum;
    float mt = (1.f - gt) * (1.f - gt);
    jt_local += fmaxf(mt + td - dneg, 0.f);
  }
  if (l == 0) {
    atomicAdd(&acc[1], jt_local * (1.f / (float)T_SEL) * maskf);
    atomicAdd(&acc[3], maskf);
  }
}

// ---------------- kernel 2: negatives row norms + bf16 convert ----------------
__global__ __launch_bounds__(256) void k_negs(const float* __restrict__ negs,
                                              float* __restrict__ nn2,
                                              unsigned short* __restrict__ neg_bf) {
  const int w = threadIdx.x >> 6;
  const int l = threadIdx.x & 63;
  const int row = blockIdx.x * 4 + w;
  const float4* nr = (const float4*)(negs + (size_t)row * D_DIM);
  ushort4* outb = (ushort4*)(neg_bf + (size_t)row * D_DIM);
  float s2 = 0.f;
#pragma unroll
  for (int i = 0; i < 3; ++i) {
    float4 x = nr[i * 64 + l];
    s2 += x.x * x.x + x.y * x.y + x.z * x.z + x.w * x.w;
    ushort4 us;
    us.x = f2bf(x.x); us.y = f2bf(x.y); us.z = f2bf(x.z); us.w = f2bf(x.w);
    outb[i * 64 + l] = us;
  }
  s2 = wave_sum(s2);
  if (l == 0) nn2[row] = s2;
}

// ---------------- kernel 3: ortho = sum((F F^T - I)^2) ----------------
__global__ __launch_bounds__(256) void k_ortho(const float* __restrict__ F,
                                               float* __restrict__ acc) {
  const int w = threadIdx.x >> 6;
  const int l = threadIdx.x & 63;
  const int p = blockIdx.x * 4 + w;  // 0..4095
  const int i = p >> 6, j = p & 63;
  const float4* Fi = (const float4*)(F + (size_t)i * D_DIM);
  const float4* Fj = (const float4*)(F + (size_t)j * D_DIM);
  float d = 0.f;
#pragma unroll
  for (int q = 0; q < 3; ++q) {
    float4 a = Fi[q * 64 + l];
    float4 b = Fj[q * 64 + l];
    d += a.x * b.x + a.y * b.y + a.z * b.z + a.w * b.w;
  }
  d = wave_sum(d);
  if (l == 0) {
    d -= (i == j) ? 1.f : 0.f;
    atomicAdd(&acc[2], d * d);
  }
}

// ---------------- kernel 4: bf16 MFMA GEMM (vhat @ negs^T) + fused hinge ----------------
// BM=128, BN=64, BK=32, 256 threads (4 waves, 2x2), wave tile 64x32.
__global__ __launch_bounds__(256) void k_gemm(
    const unsigned short* __restrict__ Abf, const unsigned short* __restrict__ Bbf,
    const float* __restrict__ nv2, const float* __restrict__ nn2,
    const float* __restrict__ true_d, const int* __restrict__ mask,
    float* __restrict__ acc) {
  __shared__ char smem[12288];  // A: 128x32 bf16 = 8192 B, B: 64x32 bf16 = 4096 B
  char* sA = smem;
  char* sB = smem + 8192;

  const int tid = threadIdx.x;
  const int w = tid >> 6;
  const int l = tid & 63;
  const int bid = blockIdx.x;
  const int tm = bid & 31;   // 32 M-tiles
  const int tn = bid >> 5;   // 16 N-tiles
  const int row0 = tm * 128;
  const int col0 = tn * 64;
  const int wr = w >> 1, wc = w & 1;

  f32x4v accf[4][2] = {};

  for (int kt = 0; kt < 24; ++kt) {
    const int k0 = kt * 32;
    if (kt) __syncthreads();
    // stage: 12 chunks of 1 KB (A chunks 0..7, B chunks 8..11); wave w does {w, w+4, w+8}
#pragma unroll
    for (int i = 0; i < 3; ++i) {
      const int c = w + i * 4;
      const int cl = (c < 8) ? c : (c - 8);
      const int rr = cl * 16 + (l >> 2);
      const int s = l & 3;
      const int ss = s ^ ((rr ^ (rr >> 2)) & 3);  // inverse source swizzle
      if (c < 8) {
        const void* gp = Abf + ((size_t)(row0 + rr) * D_DIM + k0 + ss * 8);
        async_copy16(sA + c * 1024, gp);
      } else {
        const void* gp = Bbf + ((size_t)(col0 + rr) * D_DIM + k0 + ss * 8);
        async_copy16(sB + (c - 8) * 1024, gp);
      }
    }
    __syncthreads();

    const int fr = l & 15, fq = l >> 4;
    bf16x8 af[4], bfr[2];
#pragma unroll
    for (int m = 0; m < 4; ++m) {
      const int rr = wr * 64 + m * 16 + fr;
      const int off = rr * 64 + ((fq ^ ((rr ^ (rr >> 2)) & 3)) * 16);
      af[m] = *(const bf16x8*)(sA + off);
    }
#pragma unroll
    for (int n = 0; n < 2; ++n) {
      const int rr = wc * 32 + n * 16 + fr;
      const int off = rr * 64 + ((fq ^ ((rr ^ (rr >> 2)) & 3)) * 16);
      bfr[n] = *(const bf16x8*)(sB + off);
    }
#pragma unroll
    for (int m = 0; m < 4; ++m)
#pragma unroll
      for (int n = 0; n < 2; ++n)
        accf[m][n] = __builtin_amdgcn_mfma_f32_16x16x32_bf16(af[m], bfr[n], accf[m][n], 0, 0, 0);
  }

  // fused hinge epilogue: h = max(1 + true_d - sqrt(max(d2,0)+eps), 0) * maskf
  const int fr = l & 15, fq = l >> 4;
  float local = 0.f;
#pragma unroll
  for (int m = 0; m < 4; ++m) {
#pragma unroll
    for (int j = 0; j < 4; ++j) {
      const int grow = row0 + wr * 64 + m * 16 + fq * 4 + j;
      const float nv = nv2[grow];
      const float td = true_d[grow];
      const float mf = (float)mask[grow];
#pragma unroll
      for (int n = 0; n < 2; ++n) {
        const int gcol = col0 + wc * 32 + n * 16 + fr;
        const float s = accf[m][n][j];
        const float d2 = nv + nn2[gcol] - 2.f * s;
        const float dn = sqrtf(fmaxf(d2, 0.f) + 1e-8f);
        local += mf * fmaxf(1.f + td - dn, 0.f);
      }
    }
  }
  local = wave_sum(local);
  if (l == 0) atomicAdd(&acc[0], local);
}

// ---------------- kernel 5: final combine ----------------
__global__ void k_final(const float* __restrict__ acc, float* __restrict__ out) {
  if (threadIdx.x == 0 && blockIdx.x == 0) {
    const float msum = fmaxf(acc[3], 1.0f);
    const float ju = acc[0] / (1024.f * msum);
    const float jt = acc[1] / msum;
    const float ortho = 0.01f * acc[2];
    out[0] = ju + jt + ortho;
  }
}

extern "C" void kernel_launch(void* const* d_in, const int* in_sizes, int n_in,
                              void* d_out, int out_size, void* d_ws, size_t ws_size,
                              hipStream_t stream) {
  const float* v = (const float*)d_in[0];
  const float* vhat = (const float*)d_in[1];
  const float* g = (const float*)d_in[2];
  const float* F = (const float*)d_in[3];
  const float* negs = (const float*)d_in[4];
  const int* mask = (const int*)d_in[5];
  float* out = (float*)d_out;

  char* ws = (char*)d_ws;
  float* acc = (float*)ws;                                        // 4 f32
  float* nv2 = (float*)(ws + 256);                                // 4096 f32
  float* true_d = (float*)(ws + 256 + 16384);                     // 4096 f32
  float* nn2 = (float*)(ws + 256 + 32768);                        // 1024 f32
  unsigned short* vhat_bf = (unsigned short*)(ws + 256 + 32768 + 4096);            // 4096x768 bf16
  unsigned short* neg_bf = (unsigned short*)(ws + 256 + 32768 + 4096 + 6291456);   // 1024x768 bf16

  hipMemsetAsync(acc, 0, 16, stream);
  hipLaunchKernelGGL(k_rows, dim3(1024), dim3(256), 0, stream, v, vhat, g, F, mask,
                     nv2, true_d, vhat_bf, acc);
  hipLaunchKernelGGL(k_negs, dim3(256), dim3(256), 0, stream, negs, nn2, neg_bf);
  hipLaunchKernelGGL(k_ortho, dim3(1024), dim3(256), 0, stream, F, acc);
  hipLaunchKernelGGL(k_gemm, dim3(512), dim3(256), 0, stream, vhat_bf, neg_bf,
                     nv2, nn2, true_d, mask, acc);
  hipLaunchKernelGGL(k_final, dim3(1), dim3(64), 0, stream, acc, out);
}

// Round 2
// 111.314 us; speedup vs baseline: 2.5877x; 2.5877x over previous
//
#include <hip/hip_runtime.h>
#include <math.h>

#define KD 768
#define T_SEL 8

typedef float f32x4v __attribute__((ext_vector_type(4)));
typedef __bf16 bf16x8 __attribute__((ext_vector_type(8)));

__device__ __forceinline__ float wave_sum(float x) {
#pragma unroll
  for (int o = 32; o > 0; o >>= 1) x += __shfl_xor(x, o, 64);
  return x;
}

__device__ __forceinline__ unsigned short f2bf(float x) {
  unsigned int u = __float_as_uint(x);
  unsigned int r = (u + 0x7fffu + ((u >> 16) & 1u)) >> 16;
  return (unsigned short)r;
}

__device__ __forceinline__ ushort4 cvt4(float4 a) {
  ushort4 us;
  us.x = f2bf(a.x); us.y = f2bf(a.y); us.z = f2bf(a.z); us.w = f2bf(a.w);
  return us;
}

__device__ __forceinline__ void async_copy16(void* lds, const void* g) {
  __builtin_amdgcn_global_load_lds(
      (const __attribute__((address_space(1))) unsigned int*)g,
      (__attribute__((address_space(3))) unsigned int*)lds, 16, 0, 0);
}

// ---------------- kernel 1: streaming prep (norms + bf16 convert + pad) ----------------
// rows: [0,4096) vhat/v  [4096,5120) negatives  [5120,5184) F  [5184,5248) zero-pad A
__global__ __launch_bounds__(256) void k_prep(
    const float* __restrict__ v, const float* __restrict__ vhat,
    const float* __restrict__ negs, const float* __restrict__ F,
    unsigned short* __restrict__ A_bf, unsigned short* __restrict__ B_bf,
    float* __restrict__ nv2, float* __restrict__ true_d,
    float* __restrict__ colBn) {
  const int w = threadIdx.x >> 6, l = threadIdx.x & 63;
  const int row = blockIdx.x * 4 + w;
  if (row < 4096) {
    const float4* vr = (const float4*)(vhat + (size_t)row * KD);
    const float4* vv = (const float4*)(v + (size_t)row * KD);
    ushort4* outb = (ushort4*)(A_bf + (size_t)row * KD);
    float s2 = 0.f, td2 = 0.f;
#pragma unroll
    for (int i = 0; i < 3; ++i) {
      float4 a = vr[i * 64 + l];
      float4 b = vv[i * 64 + l];
      s2 += a.x * a.x + a.y * a.y + a.z * a.z + a.w * a.w;
      float dx = a.x - b.x, dy = a.y - b.y, dz = a.z - b.z, dw = a.w - b.w;
      td2 += dx * dx + dy * dy + dz * dz + dw * dw;
      outb[i * 64 + l] = cvt4(a);
    }
    s2 = wave_sum(s2);
    td2 = wave_sum(td2);
    if (l == 0) {
      nv2[row] = s2;
      true_d[row] = sqrtf(fmaxf(td2, 0.f) + 1e-8f);
    }
  } else if (row < 5120) {
    const int r = row - 4096;
    const float4* nr = (const float4*)(negs + (size_t)r * KD);
    ushort4* outb = (ushort4*)(B_bf + (size_t)r * KD);
    float s2 = 0.f;
#pragma unroll
    for (int i = 0; i < 3; ++i) {
      float4 a = nr[i * 64 + l];
      s2 += a.x * a.x + a.y * a.y + a.z * a.z + a.w * a.w;
      outb[i * 64 + l] = cvt4(a);
    }
    s2 = wave_sum(s2);
    if (l == 0) colBn[r] = s2;
  } else if (row < 5184) {
    const int r = row - 5120;
    const float4* fr4 = (const float4*)(F + (size_t)r * KD);
    ushort4* ob1 = (ushort4*)(B_bf + (size_t)(1024 + r) * KD);
    ushort4* ob2 = (ushort4*)(A_bf + (size_t)(4096 + r) * KD);
    float s2 = 0.f;
#pragma unroll
    for (int i = 0; i < 3; ++i) {
      float4 a = fr4[i * 64 + l];
      s2 += a.x * a.x + a.y * a.y + a.z * a.z + a.w * a.w;
      ushort4 us = cvt4(a);
      ob1[i * 64 + l] = us;
      ob2[i * 64 + l] = us;
    }
    s2 = wave_sum(s2);
    if (l == 0) colBn[1024 + r] = s2;
  } else {
    const int r = row - 5184;
    ushort4* outb = (ushort4*)(A_bf + (size_t)(4160 + r) * KD);
    ushort4 z; z.x = 0; z.y = 0; z.z = 0; z.w = 0;
#pragma unroll
    for (int i = 0; i < 3; ++i) outb[i * 64 + l] = z;
  }
}

// ---------------- kernel 2: bf16 MFMA GEMM with region epilogues ----------------
// M=4224 (33x128), N=1088 (17x64), K=768 (24x32). 256 threads, 4 waves (2x2), wave tile 64x32.
__global__ __launch_bounds__(256) void k_gemm(
    const unsigned short* __restrict__ Abf, const unsigned short* __restrict__ Bbf,
    const float* __restrict__ nv2, const float* __restrict__ colBn,
    const float* __restrict__ true_d, const int* __restrict__ mask,
    float* __restrict__ S, float* __restrict__ gemm_part, float* __restrict__ or_sum) {
  __shared__ char smem[12288];  // A: 128x32 bf16 = 8192 B, B: 64x32 bf16 = 4096 B
  char* sA = smem;
  char* sB = smem + 8192;

  const int tid = threadIdx.x;
  const int w = tid >> 6;
  const int l = tid & 63;
  const int bid = blockIdx.x;
  const int tm = bid % 33;
  const int tn = bid / 33;

  if (tm == 32 && tn < 16) {  // F-rows x negative-cols: unused region
    if (tid == 0) gemm_part[bid] = 0.f;
    return;
  }

  const int row0 = tm * 128;
  const int col0 = tn * 64;
  const int wr = w >> 1, wc = w & 1;

  f32x4v accf[4][2] = {};

  for (int kt = 0; kt < 24; ++kt) {
    const int k0 = kt * 32;
    if (kt) __syncthreads();
#pragma unroll
    for (int i = 0; i < 3; ++i) {
      const int c = w + i * 4;
      const int cl = (c < 8) ? c : (c - 8);
      const int rr = cl * 16 + (l >> 2);
      const int s = l & 3;
      const int ss = s ^ ((rr ^ (rr >> 2)) & 3);  // inverse source swizzle
      if (c < 8) {
        const void* gp = Abf + ((size_t)(row0 + rr) * KD + k0 + ss * 8);
        async_copy16(sA + c * 1024, gp);
      } else {
        const void* gp = Bbf + ((size_t)(col0 + rr) * KD + k0 + ss * 8);
        async_copy16(sB + (c - 8) * 1024, gp);
      }
    }
    __syncthreads();

    const int fr = l & 15, fq = l >> 4;
    bf16x8 af[4], bfr[2];
#pragma unroll
    for (int m = 0; m < 4; ++m) {
      const int rr = wr * 64 + m * 16 + fr;
      const int off = rr * 64 + ((fq ^ ((rr ^ (rr >> 2)) & 3)) * 16);
      af[m] = *(const bf16x8*)(sA + off);
    }
#pragma unroll
    for (int n = 0; n < 2; ++n) {
      const int rr = wc * 32 + n * 16 + fr;
      const int off = rr * 64 + ((fq ^ ((rr ^ (rr >> 2)) & 3)) * 16);
      bfr[n] = *(const bf16x8*)(sB + off);
    }
#pragma unroll
    for (int m = 0; m < 4; ++m)
#pragma unroll
      for (int n = 0; n < 2; ++n)
        accf[m][n] = __builtin_amdgcn_mfma_f32_16x16x32_bf16(af[m], bfr[n], accf[m][n], 0, 0, 0);
  }

  const int fr = l & 15, fq = l >> 4;
  float local = 0.f;
  if (tm < 32 && tn < 16) {
    // Ju hinge: h = mask * max(1 + true_d - sqrt(max(d2,0)+eps), 0)
#pragma unroll
    for (int m = 0; m < 4; ++m) {
#pragma unroll
      for (int j = 0; j < 4; ++j) {
        const int grow = row0 + wr * 64 + m * 16 + fq * 4 + j;
        const float nv = nv2[grow];
        const float td = true_d[grow];
        const float mf = (float)mask[grow];
#pragma unroll
        for (int n = 0; n < 2; ++n) {
          const int gcol = col0 + wc * 32 + n * 16 + fr;
          const float s = accf[m][n][j];
          const float d2 = nv + colBn[gcol] - 2.f * s;
          const float dn = sqrtf(fmaxf(d2, 0.f) + 1e-8f);
          local += mf * fmaxf(1.f + td - dn, 0.f);
        }
      }
    }
  } else if (tm < 32) {
    // S store: vhat . F_k
#pragma unroll
    for (int m = 0; m < 4; ++m) {
#pragma unroll
      for (int j = 0; j < 4; ++j) {
        const int grow = row0 + wr * 64 + m * 16 + fq * 4 + j;
#pragma unroll
        for (int n = 0; n < 2; ++n) {
          const int gcol = col0 + wc * 32 + n * 16 + fr;
          S[(size_t)grow * 64 + (gcol - 1024)] = accf[m][n][j];
        }
      }
    }
  } else {
    // ortho: F F^T - I, rows 4096..4159 only
#pragma unroll
    for (int m = 0; m < 4; ++m) {
#pragma unroll
      for (int j = 0; j < 4; ++j) {
        const int grow = row0 + wr * 64 + m * 16 + fq * 4 + j;
        if (grow < 4160) {
          const int i2 = grow - 4096;
#pragma unroll
          for (int n = 0; n < 2; ++n) {
            const int gcol = col0 + wc * 32 + n * 16 + fr;
            const int j2 = gcol - 1024;
            const float d = accf[m][n][j] - ((i2 == j2) ? 1.f : 0.f);
            local += d * d;
          }
        }
      }
    }
  }

  local = wave_sum(local);
  __syncthreads();
  float* red = (float*)smem;
  if (l == 0) red[w] = local;
  __syncthreads();
  if (tid == 0) {
    const float t = red[0] + red[1] + red[2] + red[3];
    if (tm == 32) {
      or_sum[0] = t;
      gemm_part[bid] = 0.f;
    } else {
      gemm_part[bid] = (tn < 16) ? t : 0.f;
    }
  }
}

// ---------------- kernel 3: Jt via rank-based top-8 ----------------
__global__ __launch_bounds__(256) void k_jt(
    const float* __restrict__ g, const float* __restrict__ S,
    const float* __restrict__ nv2, const float* __restrict__ true_d,
    const float* __restrict__ colBn, const int* __restrict__ mask,
    float* __restrict__ jt_part, float* __restrict__ ms_part) {
  const int w = threadIdx.x >> 6, l = threadIdx.x & 63;
  const int row = blockIdx.x * 4 + w;
  const float gl = g[(size_t)row * 64 + l];
  int rank = 0;
#pragma unroll
  for (int d = 1; d < 64; ++d) {
    const float o = __shfl_xor(gl, d, 64);
    const int j = l ^ d;
    rank += (o < gl || (o == gl && j < l)) ? 1 : 0;
  }
  const bool sel = rank < T_SEL;
  const float gsum = wave_sum(sel ? gl : 0.f) + 1e-10f;
  const float s = S[(size_t)row * 64 + l];
  const float d2 = nv2[row] + colBn[1024 + l] - 2.f * s;
  const float dneg = sqrtf(fmaxf(d2, 0.f) + 1e-8f);
  const float gt = gl / gsum;
  const float mt = (1.f - gt) * (1.f - gt);
  const float td = true_d[row];
  const float term = sel ? fmaxf(mt + td - dneg, 0.f) : 0.f;
  const float jt = wave_sum(term);
  const float mf = (float)mask[row];

  __shared__ float red[2][4];
  if (l == 0) {
    red[0][w] = jt * mf;
    red[1][w] = mf;
  }
  __syncthreads();
  if (threadIdx.x == 0) {
    jt_part[blockIdx.x] = red[0][0] + red[0][1] + red[0][2] + red[0][3];
    ms_part[blockIdx.x] = red[1][0] + red[1][1] + red[1][2] + red[1][3];
  }
}

// ---------------- kernel 4: final combine ----------------
__global__ __launch_bounds__(256) void k_final(
    const float* __restrict__ jt_part, const float* __restrict__ ms_part,
    const float* __restrict__ gemm_part, const float* __restrict__ or_sum,
    float* __restrict__ out) {
  const int tid = threadIdx.x;
  float sj = 0.f, sm = 0.f, su = 0.f;
  for (int i = tid; i < 1024; i += 256) {
    sj += jt_part[i];
    sm += ms_part[i];
  }
  for (int i = tid; i < 561; i += 256) su += gemm_part[i];
  sj = wave_sum(sj);
  sm = wave_sum(sm);
  su = wave_sum(su);
  __shared__ float r[3][4];
  const int w = tid >> 6, l = tid & 63;
  if (l == 0) { r[0][w] = sj; r[1][w] = sm; r[2][w] = su; }
  __syncthreads();
  if (tid == 0) {
    const float jt = r[0][0] + r[0][1] + r[0][2] + r[0][3];
    float ms = r[1][0] + r[1][1] + r[1][2] + r[1][3];
    const float ju = r[2][0] + r[2][1] + r[2][2] + r[2][3];
    ms = fmaxf(ms, 1.f);
    out[0] = ju / (1024.f * ms) + jt / (8.f * ms) + 0.01f * or_sum[0];
  }
}

extern "C" void kernel_launch(void* const* d_in, const int* in_sizes, int n_in,
                              void* d_out, int out_size, void* d_ws, size_t ws_size,
                              hipStream_t stream) {
  const float* v = (const float*)d_in[0];
  const float* vhat = (const float*)d_in[1];
  const float* g = (const float*)d_in[2];
  const float* F = (const float*)d_in[3];
  const float* negs = (const float*)d_in[4];
  const int* mask = (const int*)d_in[5];
  float* out = (float*)d_out;

  char* ws = (char*)d_ws;
  float* true_d = (float*)(ws + 0);                 // 4096 f32
  float* nv2 = (float*)(ws + 16384);                // 4096 f32
  float* colBn = (float*)(ws + 32768);              // 1088 f32
  float* jt_part = (float*)(ws + 37120);            // 1024 f32
  float* ms_part = (float*)(ws + 41216);            // 1024 f32
  float* gemm_part = (float*)(ws + 45312);          // 561 f32 (pad to 2304 B)
  float* or_sum = (float*)(ws + 47616);             // 1 f32
  float* S = (float*)(ws + 49152);                  // 4096*64 f32 = 1 MB
  unsigned short* A_bf = (unsigned short*)(ws + 1097728);  // 4224x768 bf16 = 6.49 MB
  unsigned short* B_bf = (unsigned short*)(ws + 7585792);  // 1088x768 bf16 = 1.67 MB

  hipLaunchKernelGGL(k_prep, dim3(1312), dim3(256), 0, stream, v, vhat, negs, F,
                     A_bf, B_bf, nv2, true_d, colBn);
  hipLaunchKernelGGL(k_gemm, dim3(561), dim3(256), 0, stream, A_bf, B_bf,
                     nv2, colBn, true_d, mask, S, gemm_part, or_sum);
  hipLaunchKernelGGL(k_jt, dim3(1024), dim3(256), 0, stream, g, S, nv2, true_d,
                     colBn, mask, jt_part, ms_part);
  hipLaunchKernelGGL(k_final, dim3(1), dim3(256), 0, stream, jt_part, ms_part,
                     gemm_part, or_sum, out);
}

// Round 3
// 108.104 us; speedup vs baseline: 2.6646x; 1.0297x over previous
//
#include <hip/hip_runtime.h>
#include <math.h>

#define KD 768
#define T_SEL 8

typedef float f32x4v __attribute__((ext_vector_type(4)));
typedef __bf16 bf16x8 __attribute__((ext_vector_type(8)));

__device__ __forceinline__ float wave_sum(float x) {
#pragma unroll
  for (int o = 32; o > 0; o >>= 1) x += __shfl_xor(x, o, 64);
  return x;
}

__device__ __forceinline__ unsigned short f2bf(float x) {
  unsigned int u = __float_as_uint(x);
  unsigned int r = (u + 0x7fffu + ((u >> 16) & 1u)) >> 16;
  return (unsigned short)r;
}

__device__ __forceinline__ ushort4 cvt4(float4 a) {
  ushort4 us;
  us.x = f2bf(a.x); us.y = f2bf(a.y); us.z = f2bf(a.z); us.w = f2bf(a.w);
  return us;
}

__device__ __forceinline__ void async_copy16(void* lds, const void* g) {
  __builtin_amdgcn_global_load_lds(
      (const __attribute__((address_space(1))) unsigned int*)g,
      (__attribute__((address_space(3))) unsigned int*)lds, 16, 0, 0);
}

// ---------------- kernel 1: streaming prep (norms + bf16 convert + pad) ----------------
// rows: [0,4096) vhat/v  [4096,5120) negatives  [5120,5184) F  [5184,5248) zero-pad A
__global__ __launch_bounds__(256) void k_prep(
    const float* __restrict__ v, const float* __restrict__ vhat,
    const float* __restrict__ negs, const float* __restrict__ F,
    unsigned short* __restrict__ A_bf, unsigned short* __restrict__ B_bf,
    float* __restrict__ nv2, float* __restrict__ true_d,
    float* __restrict__ colBn) {
  const int w = threadIdx.x >> 6, l = threadIdx.x & 63;
  const int row = blockIdx.x * 4 + w;
  if (row < 4096) {
    const float4* vr = (const float4*)(vhat + (size_t)row * KD);
    const float4* vv = (const float4*)(v + (size_t)row * KD);
    ushort4* outb = (ushort4*)(A_bf + (size_t)row * KD);
    float s2 = 0.f, td2 = 0.f;
#pragma unroll
    for (int i = 0; i < 3; ++i) {
      float4 a = vr[i * 64 + l];
      float4 b = vv[i * 64 + l];
      s2 += a.x * a.x + a.y * a.y + a.z * a.z + a.w * a.w;
      float dx = a.x - b.x, dy = a.y - b.y, dz = a.z - b.z, dw = a.w - b.w;
      td2 += dx * dx + dy * dy + dz * dz + dw * dw;
      outb[i * 64 + l] = cvt4(a);
    }
    s2 = wave_sum(s2);
    td2 = wave_sum(td2);
    if (l == 0) {
      nv2[row] = s2;
      true_d[row] = sqrtf(fmaxf(td2, 0.f) + 1e-8f);
    }
  } else if (row < 5120) {
    const int r = row - 4096;
    const float4* nr = (const float4*)(negs + (size_t)r * KD);
    ushort4* outb = (ushort4*)(B_bf + (size_t)r * KD);
    float s2 = 0.f;
#pragma unroll
    for (int i = 0; i < 3; ++i) {
      float4 a = nr[i * 64 + l];
      s2 += a.x * a.x + a.y * a.y + a.z * a.z + a.w * a.w;
      outb[i * 64 + l] = cvt4(a);
    }
    s2 = wave_sum(s2);
    if (l == 0) colBn[r] = s2;
  } else if (row < 5184) {
    const int r = row - 5120;
    const float4* fr4 = (const float4*)(F + (size_t)r * KD);
    ushort4* ob1 = (ushort4*)(B_bf + (size_t)(1024 + r) * KD);
    ushort4* ob2 = (ushort4*)(A_bf + (size_t)(4096 + r) * KD);
    float s2 = 0.f;
#pragma unroll
    for (int i = 0; i < 3; ++i) {
      float4 a = fr4[i * 64 + l];
      s2 += a.x * a.x + a.y * a.y + a.z * a.z + a.w * a.w;
      ushort4 us = cvt4(a);
      ob1[i * 64 + l] = us;
      ob2[i * 64 + l] = us;
    }
    s2 = wave_sum(s2);
    if (l == 0) colBn[1024 + r] = s2;
  } else {
    const int r = row - 5184;
    ushort4* outb = (ushort4*)(A_bf + (size_t)(4160 + r) * KD);
    ushort4 z; z.x = 0; z.y = 0; z.z = 0; z.w = 0;
#pragma unroll
    for (int i = 0; i < 3; ++i) outb[i * 64 + l] = z;
  }
}

// ---------------- kernel 2: bf16 MFMA GEMM with region epilogues ----------------
// M=4224 (33x128), N=1088 (17x64), K=768 (12x64). 256 threads, 4 waves (2x2),
// wave tile 64x32, BK=64 (16 MFMA/wave per K-step, 2-way-max LDS aliasing).
__global__ __launch_bounds__(256) void k_gemm(
    const unsigned short* __restrict__ Abf, const unsigned short* __restrict__ Bbf,
    const float* __restrict__ nv2, const float* __restrict__ colBn,
    const float* __restrict__ true_d, const int* __restrict__ mask,
    float* __restrict__ S, float* __restrict__ gemm_part, float* __restrict__ or_sum) {
  __shared__ char smem[24576];  // A: 128 rows x 128B = 16 KB, B: 64 rows x 128B = 8 KB
  char* sA = smem;
  char* sB = smem + 16384;

  const int tid = threadIdx.x;
  const int w = tid >> 6;
  const int l = tid & 63;
  const int bid = blockIdx.x;
  const int tm = bid % 33;
  const int tn = bid / 33;

  if (tm == 32 && tn < 16) {  // F-rows x negative-cols: unused region
    if (tid == 0) gemm_part[bid] = 0.f;
    return;
  }

  const int row0 = tm * 128;
  const int col0 = tn * 64;
  const int wr = w >> 1, wc = w & 1;
  const int lr = l >> 3;  // row within an 8-row 1KB chunk
  const int sl = l & 7;   // 16B slot within a 128B row

  f32x4v accf[4][2] = {};

  for (int kt = 0; kt < 12; ++kt) {
    const int k0 = kt * 64;
    if (kt) __syncthreads();
    // stage 24 chunks of 1KB (A: 0..15, B: 16..23); wave w does {w, w+4, ..., w+20}
#pragma unroll
    for (int i = 0; i < 6; ++i) {
      const int c = w + i * 4;
      if (c < 16) {
        const int rr = c * 8 + lr;
        const int ss = sl ^ (rr & 7);  // inverse source swizzle (linear LDS dest)
        async_copy16(sA + c * 1024, Abf + ((size_t)(row0 + rr) * KD + k0 + ss * 8));
      } else {
        const int cc = c - 16;
        const int rr = cc * 8 + lr;
        const int ss = sl ^ (rr & 7);
        async_copy16(sB + cc * 1024, Bbf + ((size_t)(col0 + rr) * KD + k0 + ss * 8));
      }
    }
    __syncthreads();

    const int fr = l & 15, fq = l >> 4;
#pragma unroll
    for (int kk = 0; kk < 2; ++kk) {
      bf16x8 af[4], bfr[2];
#pragma unroll
      for (int m = 0; m < 4; ++m) {
        const int rr = wr * 64 + m * 16 + fr;
        const int slot = (fq + kk * 4) ^ (rr & 7);
        af[m] = *(const bf16x8*)(sA + rr * 128 + slot * 16);
      }
#pragma unroll
      for (int n = 0; n < 2; ++n) {
        const int rr = wc * 32 + n * 16 + fr;
        const int slot = (fq + kk * 4) ^ (rr & 7);
        bfr[n] = *(const bf16x8*)(sB + rr * 128 + slot * 16);
      }
#pragma unroll
      for (int m = 0; m < 4; ++m)
#pragma unroll
        for (int n = 0; n < 2; ++n)
          accf[m][n] = __builtin_amdgcn_mfma_f32_16x16x32_bf16(af[m], bfr[n], accf[m][n], 0, 0, 0);
    }
  }

  const int fr = l & 15, fq = l >> 4;
  float local = 0.f;
  if (tm < 32 && tn < 16) {
    // Ju hinge: h = mask * max(1 + true_d - sqrt(max(d2,0)+eps), 0)
#pragma unroll
    for (int m = 0; m < 4; ++m) {
#pragma unroll
      for (int j = 0; j < 4; ++j) {
        const int grow = row0 + wr * 64 + m * 16 + fq * 4 + j;
        const float nv = nv2[grow];
        const float td = true_d[grow];
        const float mf = (float)mask[grow];
#pragma unroll
        for (int n = 0; n < 2; ++n) {
          const int gcol = col0 + wc * 32 + n * 16 + fr;
          const float s = accf[m][n][j];
          const float d2 = nv + colBn[gcol] - 2.f * s;
          const float dn = sqrtf(fmaxf(d2, 0.f) + 1e-8f);
          local += mf * fmaxf(1.f + td - dn, 0.f);
        }
      }
    }
  } else if (tm < 32) {
    // S store: vhat . F_k
#pragma unroll
    for (int m = 0; m < 4; ++m) {
#pragma unroll
      for (int j = 0; j < 4; ++j) {
        const int grow = row0 + wr * 64 + m * 16 + fq * 4 + j;
#pragma unroll
        for (int n = 0; n < 2; ++n) {
          const int gcol = col0 + wc * 32 + n * 16 + fr;
          S[(size_t)grow * 64 + (gcol - 1024)] = accf[m][n][j];
        }
      }
    }
  } else {
    // ortho: F F^T - I, rows 4096..4159 only
#pragma unroll
    for (int m = 0; m < 4; ++m) {
#pragma unroll
      for (int j = 0; j < 4; ++j) {
        const int grow = row0 + wr * 64 + m * 16 + fq * 4 + j;
        if (grow < 4160) {
          const int i2 = grow - 4096;
#pragma unroll
          for (int n = 0; n < 2; ++n) {
            const int gcol = col0 + wc * 32 + n * 16 + fr;
            const int j2 = gcol - 1024;
            const float d = accf[m][n][j] - ((i2 == j2) ? 1.f : 0.f);
            local += d * d;
          }
        }
      }
    }
  }

  local = wave_sum(local);
  __syncthreads();
  float* red = (float*)smem;
  if (l == 0) red[w] = local;
  __syncthreads();
  if (tid == 0) {
    const float t = red[0] + red[1] + red[2] + red[3];
    if (tm == 32) {
      or_sum[0] = t;
      gemm_part[bid] = 0.f;
    } else {
      gemm_part[bid] = (tn < 16) ? t : 0.f;
    }
  }
}

// ---------------- kernel 3: Jt via rank-based top-8 ----------------
__global__ __launch_bounds__(256) void k_jt(
    const float* __restrict__ g, const float* __restrict__ S,
    const float* __restrict__ nv2, const float* __restrict__ true_d,
    const float* __restrict__ colBn, const int* __restrict__ mask,
    float* __restrict__ jt_part, float* __restrict__ ms_part) {
  const int w = threadIdx.x >> 6, l = threadIdx.x & 63;
  const int row = blockIdx.x * 4 + w;
  const float gl = g[(size_t)row * 64 + l];
  int rank = 0;
#pragma unroll
  for (int d = 1; d < 64; ++d) {
    const float o = __shfl_xor(gl, d, 64);
    const int j = l ^ d;
    rank += (o < gl || (o == gl && j < l)) ? 1 : 0;
  }
  const bool sel = rank < T_SEL;
  const float gsum = wave_sum(sel ? gl : 0.f) + 1e-10f;
  const float s = S[(size_t)row * 64 + l];
  const float d2 = nv2[row] + colBn[1024 + l] - 2.f * s;
  const float dneg = sqrtf(fmaxf(d2, 0.f) + 1e-8f);
  const float gt = gl / gsum;
  const float mt = (1.f - gt) * (1.f - gt);
  const float td = true_d[row];
  const float term = sel ? fmaxf(mt + td - dneg, 0.f) : 0.f;
  const float jt = wave_sum(term);
  const float mf = (float)mask[row];

  __shared__ float red[2][4];
  if (l == 0) {
    red[0][w] = jt * mf;
    red[1][w] = mf;
  }
  __syncthreads();
  if (threadIdx.x == 0) {
    jt_part[blockIdx.x] = red[0][0] + red[0][1] + red[0][2] + red[0][3];
    ms_part[blockIdx.x] = red[1][0] + red[1][1] + red[1][2] + red[1][3];
  }
}

// ---------------- kernel 4: final combine ----------------
__global__ __launch_bounds__(256) void k_final(
    const float* __restrict__ jt_part, const float* __restrict__ ms_part,
    const float* __restrict__ gemm_part, const float* __restrict__ or_sum,
    float* __restrict__ out) {
  const int tid = threadIdx.x;
  float sj = 0.f, sm = 0.f, su = 0.f;
  for (int i = tid; i < 1024; i += 256) {
    sj += jt_part[i];
    sm += ms_part[i];
  }
  for (int i = tid; i < 561; i += 256) su += gemm_part[i];
  sj = wave_sum(sj);
  sm = wave_sum(sm);
  su = wave_sum(su);
  __shared__ float r[3][4];
  const int w = tid >> 6, l = tid & 63;
  if (l == 0) { r[0][w] = sj; r[1][w] = sm; r[2][w] = su; }
  __syncthreads();
  if (tid == 0) {
    const float jt = r[0][0] + r[0][1] + r[0][2] + r[0][3];
    float ms = r[1][0] + r[1][1] + r[1][2] + r[1][3];
    const float ju = r[2][0] + r[2][1] + r[2][2] + r[2][3];
    ms = fmaxf(ms, 1.f);
    out[0] = ju / (1024.f * ms) + jt / (8.f * ms) + 0.01f * or_sum[0];
  }
}

extern "C" void kernel_launch(void* const* d_in, const int* in_sizes, int n_in,
                              void* d_out, int out_size, void* d_ws, size_t ws_size,
                              hipStream_t stream) {
  const float* v = (const float*)d_in[0];
  const float* vhat = (const float*)d_in[1];
  const float* g = (const float*)d_in[2];
  const float* F = (const float*)d_in[3];
  const float* negs = (const float*)d_in[4];
  const int* mask = (const int*)d_in[5];
  float* out = (float*)d_out;

  char* ws = (char*)d_ws;
  float* true_d = (float*)(ws + 0);                 // 4096 f32
  float* nv2 = (float*)(ws + 16384);                // 4096 f32
  float* colBn = (float*)(ws + 32768);              // 1088 f32
  float* jt_part = (float*)(ws + 37120);            // 1024 f32
  float* ms_part = (float*)(ws + 41216);            // 1024 f32
  float* gemm_part = (float*)(ws + 45312);          // 561 f32 (pad to 2304 B)
  float* or_sum = (float*)(ws + 47616);             // 1 f32
  float* S = (float*)(ws + 49152);                  // 4096*64 f32 = 1 MB
  unsigned short* A_bf = (unsigned short*)(ws + 1097728);  // 4224x768 bf16 = 6.49 MB
  unsigned short* B_bf = (unsigned short*)(ws + 7585792);  // 1088x768 bf16 = 1.67 MB

  hipLaunchKernelGGL(k_prep, dim3(1312), dim3(256), 0, stream, v, vhat, negs, F,
                     A_bf, B_bf, nv2, true_d, colBn);
  hipLaunchKernelGGL(k_gemm, dim3(561), dim3(256), 0, stream, A_bf, B_bf,
                     nv2, colBn, true_d, mask, S, gemm_part, or_sum);
  hipLaunchKernelGGL(k_jt, dim3(1024), dim3(256), 0, stream, g, S, nv2, true_d,
                     colBn, mask, jt_part, ms_part);
  hipLaunchKernelGGL(k_final, dim3(1), dim3(256), 0, stream, jt_part, ms_part,
                     gemm_part, or_sum, out);
}